// Round 3
// baseline (1724.422 us; speedup 1.0000x reference)
//
#include <hip/hip_runtime.h>
#include <math.h>

#define N_NODES 100000
#define N_EDGES 3200000
#define D_FEAT 256
#define GC_HID 20
#define DEC_HID 40
#define Z_DIM 32

#define NB 1563        // buckets of 64 nodes: 1563*64 = 100032 >= N
#define BCAP 4096      // mean 2048, sigma~45 -> 45-sigma margin
// rec_r word: (local_r<<17) | sender   (6+17 = 23 bits)

// ---------------- ws layout (bytes) ----------------
// h_pre : [N*20] f32 @ 0            (8,000,000)
// agg   : [N*20] f32 @  8,000,000   (8,000,000)
// rec_s : [NB*BCAP] u16 @ 16,000,000 (12,804,096)   (later reused as zbuf [N*32] f32)
// rs_s  : [N]    f32 @ 28,810,000   (400,000)
// cur_r : [NB]   u32 @ 29,210,000   (6,252)
// cur_s : [NB]   u32 @ 29,216,252   (6,252)
// rec_r : [NB*BCAP] u32 @ 29,230,000 (25,608,192)   end = 54,838,192

__global__ void k_scat(const int* __restrict__ snd, const int* __restrict__ rcv,
                       unsigned* __restrict__ cur_r, unsigned* __restrict__ cur_s,
                       unsigned* __restrict__ rec_r, unsigned short* __restrict__ rec_s) {
    int e = blockIdx.x * 256 + threadIdx.x;
    if (e >= N_EDGES) return;
    int s = snd[e], r = rcv[e];
    int br = r >> 6;
    unsigned lr = (unsigned)(r & 63);
    unsigned pr = atomicAdd(&cur_r[br], 1u);
    if (pr < BCAP) rec_r[(size_t)br * BCAP + pr] = (lr << 17) | (unsigned)s;
    int bs = s >> 6;
    unsigned ps = atomicAdd(&cur_s[bs], 1u);
    if (ps < BCAP) rec_s[(size_t)bs * BCAP + ps] = (unsigned short)(s & 63);
}

// deg_s histogram per sender bucket -> rs_s
__global__ __launch_bounds__(256) void k_rss(const unsigned* __restrict__ cur_s,
                                             const unsigned short* __restrict__ rec_s,
                                             float* __restrict__ rs_s) {
    __shared__ unsigned h[64];
    int b = blockIdx.x, t = threadIdx.x;
    if (t < 64) h[t] = 0u;
    __syncthreads();
    unsigned cnt = min(cur_s[b], (unsigned)BCAP);
    const unsigned short* rp = rec_s + (size_t)b * BCAP;
    for (unsigned i = t; i < cnt; i += 256) atomicAdd(&h[rp[i]], 1u);
    __syncthreads();
    if (t < 64) {
        int n = b * 64 + t;
        if (n < N_NODES) rs_s[n] = rsqrtf(fmaxf((float)h[t], 1.0f));
    }
}

// bucket aggregation: dst[n] = rs_r[n] * sum_{e: rcv=n} src[snd_e], rs_r from inline count
__global__ __launch_bounds__(256) void k_agg(const unsigned* __restrict__ cur_r,
                                             const unsigned* __restrict__ rec_r,
                                             const float* __restrict__ src,
                                             float* __restrict__ dst) {
    __shared__ float acc[64 * GC_HID];
    __shared__ unsigned cl[64];
    int b = blockIdx.x, t = threadIdx.x;
    for (int i = t; i < 64 * GC_HID; i += 256) acc[i] = 0.0f;
    if (t < 64) cl[t] = 0u;
    __syncthreads();
    unsigned cnt = min(cur_r[b], (unsigned)BCAP);
    const unsigned* rp = rec_r + (size_t)b * BCAP;
    for (unsigned i = t; i < cnt; i += 256) {
        unsigned rec = rp[i];
        unsigned s  = rec & 0x1FFFFu;
        unsigned lr = rec >> 17;
        const float4* sp = (const float4*)(src + (size_t)s * GC_HID);
        float4 a = sp[0], b4 = sp[1], c = sp[2], d = sp[3], e = sp[4];
        atomicAdd(&cl[lr], 1u);
        float* row = &acc[lr * GC_HID];
        atomicAdd(row + 0,  a.x);  atomicAdd(row + 1,  a.y);
        atomicAdd(row + 2,  a.z);  atomicAdd(row + 3,  a.w);
        atomicAdd(row + 4,  b4.x); atomicAdd(row + 5,  b4.y);
        atomicAdd(row + 6,  b4.z); atomicAdd(row + 7,  b4.w);
        atomicAdd(row + 8,  c.x);  atomicAdd(row + 9,  c.y);
        atomicAdd(row + 10, c.z);  atomicAdd(row + 11, c.w);
        atomicAdd(row + 12, d.x);  atomicAdd(row + 13, d.y);
        atomicAdd(row + 14, d.z);  atomicAdd(row + 15, d.w);
        atomicAdd(row + 16, e.x);  atomicAdd(row + 17, e.y);
        atomicAdd(row + 18, e.z);  atomicAdd(row + 19, e.w);
    }
    __syncthreads();
    int nbase = b * 64;
    for (int i = t; i < 64 * GC_HID; i += 256) {
        int row = i / GC_HID;
        int n = nbase + row;
        if (n < N_NODES)
            dst[(size_t)n * GC_HID + (i % GC_HID)] =
                acc[i] * rsqrtf(fmaxf((float)cl[row], 1.0f));
    }
}

// GC layer 1 transform: h_pre[n] = softmax(relu(nodes[n] @ W1 + b1)) * rs_s[n]
__global__ __launch_bounds__(256) void k_gc1(const float* __restrict__ nodes,
                                             const float* __restrict__ W1,
                                             const float* __restrict__ b1,
                                             const float* __restrict__ rs_s,
                                             float* __restrict__ h_pre) {
    __shared__ float Wt[GC_HID][D_FEAT];
    __shared__ float bsh[GC_HID];
    int tid = threadIdx.x;
    for (int idx = tid; idx < D_FEAT * GC_HID; idx += 256) {
        int i = idx / GC_HID, j = idx - i * GC_HID;
        Wt[j][i] = W1[idx];
    }
    if (tid < GC_HID) bsh[tid] = b1[tid];
    __syncthreads();

    int lane = tid & 63;
    int w    = tid >> 6;
    for (int node = blockIdx.x * 4 + w; node < N_NODES; node += gridDim.x * 4) {
        const float4 x = ((const float4*)nodes)[node * (D_FEAT / 4) + lane];
        float p[GC_HID];
#pragma unroll
        for (int j = 0; j < GC_HID; ++j) {
            float4 wv = ((const float4*)&Wt[j][0])[lane];
            p[j] = x.x * wv.x + x.y * wv.y + x.z * wv.z + x.w * wv.w;
        }
#pragma unroll
        for (int m = 32; m >= 1; m >>= 1) {
#pragma unroll
            for (int j = 0; j < GC_HID; ++j) p[j] += __shfl_xor(p[j], m, 64);
        }
        float mx = -1e30f;
#pragma unroll
        for (int j = 0; j < GC_HID; ++j) {
            p[j] = fmaxf(p[j] + bsh[j], 0.0f);
            mx = fmaxf(mx, p[j]);
        }
        float s = 0.0f;
#pragma unroll
        for (int j = 0; j < GC_HID; ++j) {
            p[j] = __expf(p[j] - mx);
            s += p[j];
        }
        float inv = rs_s[node] / s;
#pragma unroll
        for (int j = 0; j < GC_HID; ++j) p[j] *= inv;
        if (lane == 0) {
            float4* o = (float4*)&h_pre[node * GC_HID];
            o[0] = make_float4(p[0],  p[1],  p[2],  p[3]);
            o[1] = make_float4(p[4],  p[5],  p[6],  p[7]);
            o[2] = make_float4(p[8],  p[9],  p[10], p[11]);
            o[3] = make_float4(p[12], p[13], p[14], p[15]);
            o[4] = make_float4(p[16], p[17], p[18], p[19]);
        }
    }
}

// GC layer 2 transform (input pre-scaled by rs_r): h2_pre = softmax(relu(h1@W2+b2))*rs_s
__global__ __launch_bounds__(256) void k_gc2(const float* __restrict__ h1in,
                                             const float* __restrict__ W2,
                                             const float* __restrict__ b2,
                                             const float* __restrict__ rs_s,
                                             float* __restrict__ h2_pre) {
    __shared__ float Wsh[GC_HID * GC_HID];
    __shared__ float bsh[GC_HID];
    int tid = threadIdx.x;
    if (tid < GC_HID * GC_HID) Wsh[tid] = W2[tid];
    if (tid < GC_HID) bsh[tid] = b2[tid];
    __syncthreads();
    int node = blockIdx.x * 256 + tid;
    if (node >= N_NODES) return;
    const float4* ap = (const float4*)&h1in[node * GC_HID];
    float4 a0 = ap[0], a1 = ap[1], a2 = ap[2], a3 = ap[3], a4 = ap[4];
    float h1[GC_HID] = {a0.x,a0.y,a0.z,a0.w, a1.x,a1.y,a1.z,a1.w,
                        a2.x,a2.y,a2.z,a2.w, a3.x,a3.y,a3.z,a3.w,
                        a4.x,a4.y,a4.z,a4.w};
    float t[GC_HID];
#pragma unroll
    for (int j = 0; j < GC_HID; ++j) t[j] = bsh[j];
#pragma unroll
    for (int i = 0; i < GC_HID; ++i) {
        float x = h1[i];
#pragma unroll
        for (int j = 0; j < GC_HID; ++j) t[j] = fmaf(x, Wsh[i * GC_HID + j], t[j]);
    }
    float mx = -1e30f;
#pragma unroll
    for (int j = 0; j < GC_HID; ++j) { t[j] = fmaxf(t[j], 0.0f); mx = fmaxf(mx, t[j]); }
    float s = 0.0f;
#pragma unroll
    for (int j = 0; j < GC_HID; ++j) { t[j] = __expf(t[j] - mx); s += t[j]; }
    float inv = rs_s[node] / s;
#pragma unroll
    for (int j = 0; j < GC_HID; ++j) t[j] *= inv;
    float4* o = (float4*)&h2_pre[node * GC_HID];
    o[0] = make_float4(t[0],  t[1],  t[2],  t[3]);
    o[1] = make_float4(t[4],  t[5],  t[6],  t[7]);
    o[2] = make_float4(t[8],  t[9],  t[10], t[11]);
    o[3] = make_float4(t[12], t[13], t[14], t[15]);
    o[4] = make_float4(t[16], t[17], t[18], t[19]);
}

// encoder head: hcat=[h2, nodes]; mu/logsig2; z
__global__ __launch_bounds__(256) void k_enc(const float* __restrict__ h2in,
                                             const float* __restrict__ nodes,
                                             const float* __restrict__ eps,
                                             const float* __restrict__ Wmu,
                                             const float* __restrict__ bmu,
                                             const float* __restrict__ Wls,
                                             const float* __restrict__ bls,
                                             float* __restrict__ mu_out,
                                             float* __restrict__ ls_out,
                                             float* __restrict__ z) {
    int node = blockIdx.x * 256 + threadIdx.x;
    if (node >= N_NODES) return;
    float accm[Z_DIM], accl[Z_DIM];
#pragma unroll
    for (int j = 0; j < Z_DIM; ++j) { accm[j] = bmu[j]; accl[j] = bls[j]; }

    const float4* ap = (const float4*)&h2in[node * GC_HID];
    float4 a0 = ap[0], a1 = ap[1], a2 = ap[2], a3 = ap[3], a4 = ap[4];
    float h2[GC_HID] = {a0.x,a0.y,a0.z,a0.w, a1.x,a1.y,a1.z,a1.w,
                        a2.x,a2.y,a2.z,a2.w, a3.x,a3.y,a3.z,a3.w,
                        a4.x,a4.y,a4.z,a4.w};
#pragma unroll
    for (int i = 0; i < GC_HID; ++i) {
        float x = h2[i];
#pragma unroll
        for (int j = 0; j < Z_DIM; ++j) {
            accm[j] = fmaf(x, Wmu[i * Z_DIM + j], accm[j]);
            accl[j] = fmaf(x, Wls[i * Z_DIM + j], accl[j]);
        }
    }
    const float4* np = (const float4*)&nodes[node * D_FEAT];
    for (int i4 = 0; i4 < D_FEAT / 4; ++i4) {
        float4 xx = np[i4];
        int row = GC_HID + i4 * 4;
#pragma unroll
        for (int c = 0; c < 4; ++c) {
            float x = (c == 0) ? xx.x : (c == 1) ? xx.y : (c == 2) ? xx.z : xx.w;
#pragma unroll
            for (int j = 0; j < Z_DIM; ++j) {
                accm[j] = fmaf(x, Wmu[(row + c) * Z_DIM + j], accm[j]);
                accl[j] = fmaf(x, Wls[(row + c) * Z_DIM + j], accl[j]);
            }
        }
    }
    const float4* ep = (const float4*)&eps[node * Z_DIM];
    float4* mo = (float4*)&mu_out[node * Z_DIM];
    float4* lo = (float4*)&ls_out[node * Z_DIM];
    float4* zo = (float4*)&z[node * Z_DIM];
#pragma unroll
    for (int q = 0; q < Z_DIM / 4; ++q) {
        float4 ev = ep[q];
        float4 m4 = make_float4(accm[4*q], accm[4*q+1], accm[4*q+2], accm[4*q+3]);
        float4 l4 = make_float4(accl[4*q], accl[4*q+1], accl[4*q+2], accl[4*q+3]);
        mo[q] = m4;
        lo[q] = l4;
        float4 zz;
        zz.x = m4.x + (1e-4f + __expf(0.5f * l4.x)) * ev.x;
        zz.y = m4.y + (1e-4f + __expf(0.5f * l4.y)) * ev.y;
        zz.z = m4.z + (1e-4f + __expf(0.5f * l4.z)) * ev.z;
        zz.w = m4.w + (1e-4f + __expf(0.5f * l4.w)) * ev.w;
        zo[q] = zz;
    }
}

// decoder: d = relu(z@Wd1+bd1); X = d@Wd2+bd2
__global__ __launch_bounds__(256) void k_dec(const float* __restrict__ z,
                                             const float* __restrict__ Wd1,
                                             const float* __restrict__ bd1,
                                             const float* __restrict__ Wd2,
                                             const float* __restrict__ bd2,
                                             float* __restrict__ X) {
    int node = blockIdx.x * 256 + threadIdx.x;
    if (node >= N_NODES) return;
    float zv[Z_DIM];
    const float4* zp = (const float4*)&z[node * Z_DIM];
#pragma unroll
    for (int q = 0; q < Z_DIM / 4; ++q) {
        float4 v = zp[q];
        zv[4*q] = v.x; zv[4*q+1] = v.y; zv[4*q+2] = v.z; zv[4*q+3] = v.w;
    }
    float d[DEC_HID];
#pragma unroll
    for (int j = 0; j < DEC_HID; ++j) d[j] = bd1[j];
#pragma unroll
    for (int i = 0; i < Z_DIM; ++i) {
        float x = zv[i];
#pragma unroll
        for (int j = 0; j < DEC_HID; ++j) d[j] = fmaf(x, Wd1[i * DEC_HID + j], d[j]);
    }
#pragma unroll
    for (int j = 0; j < DEC_HID; ++j) d[j] = fmaxf(d[j], 0.0f);

    float4* xp = (float4*)&X[node * D_FEAT];
    for (int ch = 0; ch < 4; ++ch) {
        float o[64];
#pragma unroll
        for (int j = 0; j < 64; ++j) o[j] = bd2[ch * 64 + j];
#pragma unroll
        for (int i = 0; i < DEC_HID; ++i) {
            float x = d[i];
#pragma unroll
            for (int j = 0; j < 64; ++j)
                o[j] = fmaf(x, Wd2[i * 256 + ch * 64 + j], o[j]);
        }
#pragma unroll
        for (int q = 0; q < 16; ++q)
            xp[ch * 16 + q] = make_float4(o[4*q], o[4*q+1], o[4*q+2], o[4*q+3]);
    }
}

extern "C" void kernel_launch(void* const* d_in, const int* in_sizes, int n_in,
                              void* d_out, int out_size, void* d_ws, size_t ws_size,
                              hipStream_t stream) {
    const float* nodes = (const float*)d_in[0];
    const int*   snd   = (const int*)d_in[1];
    const int*   rcv   = (const int*)d_in[2];
    const float* eps   = (const float*)d_in[3];
    const float* W1    = (const float*)d_in[4];
    const float* b1    = (const float*)d_in[5];
    const float* W2    = (const float*)d_in[6];
    const float* b2    = (const float*)d_in[7];
    const float* Wmu   = (const float*)d_in[8];
    const float* bmu   = (const float*)d_in[9];
    const float* Wls   = (const float*)d_in[10];
    const float* bls   = (const float*)d_in[11];
    const float* Wd1   = (const float*)d_in[12];
    const float* bd1   = (const float*)d_in[13];
    const float* Wd2   = (const float*)d_in[14];
    const float* bd2   = (const float*)d_in[15];

    char* ws = (char*)d_ws;
    float*          h_pre = (float*)(ws);
    float*          agg   = (float*)(ws + 8000000);
    unsigned short* rec_s = (unsigned short*)(ws + 16000000);  // reused as zbuf later
    float*          zbuf  = (float*)(ws + 16000000);
    float*          rs_s  = (float*)(ws + 28810000);
    unsigned*       cur_r = (unsigned*)(ws + 29210000);
    unsigned*       cur_s = (unsigned*)(ws + 29216252);
    unsigned*       rec_r = (unsigned*)(ws + 29230000);

    float* X      = (float*)d_out;
    float* mu_out = X + (size_t)N_NODES * D_FEAT;
    float* ls_out = mu_out + (size_t)N_NODES * Z_DIM;

    hipMemsetAsync(cur_r, 0, 12504, stream);  // cur_r + cur_s (contiguous)

    k_scat<<<12500, 256, 0, stream>>>(snd, rcv, cur_r, cur_s, rec_r, rec_s);
    k_rss<<<NB, 256, 0, stream>>>(cur_s, rec_s, rs_s);
    k_gc1<<<2048, 256, 0, stream>>>(nodes, W1, b1, rs_s, h_pre);
    k_agg<<<NB, 256, 0, stream>>>(cur_r, rec_r, h_pre, agg);
    k_gc2<<<391, 256, 0, stream>>>(agg, W2, b2, rs_s, h_pre);
    k_agg<<<NB, 256, 0, stream>>>(cur_r, rec_r, h_pre, agg);
    k_enc<<<391, 256, 0, stream>>>(agg, nodes, eps, Wmu, bmu, Wls, bls,
                                   mu_out, ls_out, zbuf);
    k_dec<<<391, 256, 0, stream>>>(zbuf, Wd1, bd1, Wd2, bd2, X);
}

// Round 4
// 1491.882 us; speedup vs baseline: 1.1559x; 1.1559x over previous
//
#include <hip/hip_runtime.h>
#include <math.h>

#define N_NODES 100000
#define N_EDGES 3200000
#define D_FEAT 256
#define GC_HID 20
#define DEC_HID 40
#define Z_DIM 32

#define EPB 2048          // edges per sort block
#define NBLK 1563         // ceil(3.2M / 2048); last block has 1024
#define SB 196            // node super-buckets of 512 (196*512 = 100352 >= N)
#define SBSH 9

// ---------------- ws layout (bytes) ----------------
// h_pre : [N*20] f32 @ 0            (8,000,000)
// agg   : [N*20] f32 @  8,000,000   (8,000,000)
// zbuf  : [N*32] f32 @ 16,000,000   (12,800,000)
// rec_r : u32 [NBLK*EPB] @ 28,800,000 (12,804,096)
// rec_s : u16 [NBLK*EPB] @ 41,604,096 (6,402,048)
// srow_r: u16 [NBLK*197] @ 48,006,144 (615,822)
// srow_s: u16 [NBLK*197] @ 48,622,000 (615,822)
// rs_s  : f32 [N]        @ 49,237,824 (400,000)   end = 49,637,824

// Block-local dual counting sort. Each block owns a contiguous 2048-record
// window per stream -> all global writes coalesced, zero global atomics.
__global__ __launch_bounds__(256) void k_sort(const int* __restrict__ snd,
                                              const int* __restrict__ rcv,
                                              unsigned* __restrict__ rec_r,
                                              unsigned short* __restrict__ rec_s,
                                              unsigned short* __restrict__ srow_r,
                                              unsigned short* __restrict__ srow_s) {
    __shared__ int es[EPB], er[EPB];          // 16 KB
    __shared__ unsigned scan[SB + 1];
    __shared__ unsigned cur[SB];
    __shared__ unsigned sortedr[EPB];         // 8 KB
    __shared__ unsigned short sorteds[EPB];   // 4 KB
    int b = blockIdx.x, t = threadIdx.x;
    int base = b * EPB;
    int cnt = min(EPB, N_EDGES - base);
    for (int i = t; i < cnt; i += 256) { es[i] = snd[base + i]; er[i] = rcv[base + i]; }

    // ---------- receiver stream ----------
    if (t < SB + 1) scan[t] = 0u;
    __syncthreads();
    for (int i = t; i < cnt; i += 256) atomicAdd(&scan[(er[i] >> SBSH) + 1], 1u);
    __syncthreads();
    for (int off = 1; off <= SB; off <<= 1) {
        unsigned v = (t >= off && t <= SB) ? scan[t - off] : 0u;
        __syncthreads();
        if (t <= SB) scan[t] += v;
        __syncthreads();
    }
    if (t <= SB) srow_r[b * (SB + 1) + t] = (unsigned short)scan[t];
    if (t < SB) cur[t] = scan[t];
    __syncthreads();
    for (int i = t; i < cnt; i += 256) {
        int r = er[i];
        unsigned pos = atomicAdd(&cur[r >> SBSH], 1u);
        sortedr[pos] = ((unsigned)(r & 511) << 17) | (unsigned)es[i];
    }
    __syncthreads();
    for (int i = t; i < cnt; i += 256) rec_r[base + i] = sortedr[i];
    __syncthreads();

    // ---------- sender stream ----------
    if (t < SB + 1) scan[t] = 0u;
    __syncthreads();
    for (int i = t; i < cnt; i += 256) atomicAdd(&scan[(es[i] >> SBSH) + 1], 1u);
    __syncthreads();
    for (int off = 1; off <= SB; off <<= 1) {
        unsigned v = (t >= off && t <= SB) ? scan[t - off] : 0u;
        __syncthreads();
        if (t <= SB) scan[t] += v;
        __syncthreads();
    }
    if (t <= SB) srow_s[b * (SB + 1) + t] = (unsigned short)scan[t];
    if (t < SB) cur[t] = scan[t];
    __syncthreads();
    for (int i = t; i < cnt; i += 256) {
        int s = es[i];
        unsigned pos = atomicAdd(&cur[s >> SBSH], 1u);
        sorteds[pos] = (unsigned short)(s & 511);
    }
    __syncthreads();
    for (int i = t; i < cnt; i += 256) rec_s[base + i] = sorteds[i];
}

// per-node sender-degree histogram -> rs_s
__global__ __launch_bounds__(512) void k_degs(const unsigned short* __restrict__ rec_s,
                                              const unsigned short* __restrict__ srow_s,
                                              float* __restrict__ rs_s) {
    __shared__ unsigned h[512];
    int s = blockIdx.x, t = threadIdx.x;
    h[t] = 0u;
    __syncthreads();
    int wave = t >> 6, lane = t & 63;
    for (int k = wave; k < NBLK; k += 8) {
        unsigned st = srow_s[k * (SB + 1) + s];
        unsigned en = srow_s[k * (SB + 1) + s + 1];
        const unsigned short* rp = rec_s + (size_t)k * EPB;
        for (unsigned i = st + lane; i < en; i += 64) atomicAdd(&h[rp[i]], 1u);
    }
    __syncthreads();
    int n = (s << SBSH) + t;
    if (n < N_NODES) rs_s[n] = rsqrtf(fmaxf((float)h[t], 1.0f));
}

// run-based aggregation: dst[n] = rs_r[n] * sum_{e: rcv=n} src[snd_e]
// acc stride 21 (odd) -> bank-conflict-free-ish LDS atomics.
__global__ __launch_bounds__(512) void k_aggB(const unsigned* __restrict__ rec_r,
                                              const unsigned short* __restrict__ srow_r,
                                              const float* __restrict__ src,
                                              float* __restrict__ dst) {
    __shared__ float acc[512 * 21];    // 43 KB
    __shared__ unsigned cl[512];
    int s = blockIdx.x, t = threadIdx.x;
    for (int i = t; i < 512 * 21; i += 512) acc[i] = 0.0f;
    cl[t] = 0u;
    __syncthreads();
    int wave = t >> 6, lane = t & 63;
    for (int k = wave; k < NBLK; k += 8) {
        unsigned st = srow_r[k * (SB + 1) + s];
        unsigned en = srow_r[k * (SB + 1) + s + 1];
        const unsigned* rp = rec_r + (size_t)k * EPB;
        for (unsigned i = st + lane; i < en; i += 64) {
            unsigned rec = rp[i];
            unsigned sn = rec & 0x1FFFFu;
            unsigned lr = rec >> 17;
            const float4* sp = (const float4*)(src + (size_t)sn * GC_HID);
            float4 a = sp[0], b4 = sp[1], c = sp[2], d = sp[3], e = sp[4];
            atomicAdd(&cl[lr], 1u);
            float* row = &acc[lr * 21];
            atomicAdd(row + 0,  a.x);  atomicAdd(row + 1,  a.y);
            atomicAdd(row + 2,  a.z);  atomicAdd(row + 3,  a.w);
            atomicAdd(row + 4,  b4.x); atomicAdd(row + 5,  b4.y);
            atomicAdd(row + 6,  b4.z); atomicAdd(row + 7,  b4.w);
            atomicAdd(row + 8,  c.x);  atomicAdd(row + 9,  c.y);
            atomicAdd(row + 10, c.z);  atomicAdd(row + 11, c.w);
            atomicAdd(row + 12, d.x);  atomicAdd(row + 13, d.y);
            atomicAdd(row + 14, d.z);  atomicAdd(row + 15, d.w);
            atomicAdd(row + 16, e.x);  atomicAdd(row + 17, e.y);
            atomicAdd(row + 18, e.z);  atomicAdd(row + 19, e.w);
        }
    }
    __syncthreads();
    int nbase = s << SBSH;
    for (int i = t; i < 512 * GC_HID; i += 512) {
        int row = i / GC_HID, j = i - row * GC_HID;
        int n = nbase + row;
        if (n < N_NODES)
            dst[(size_t)n * GC_HID + j] = acc[row * 21 + j] * rsqrtf(fmaxf((float)cl[row], 1.0f));
    }
}

// GC layer 1 transform: h_pre[n] = softmax(relu(nodes[n] @ W1 + b1)) * rs_s[n]
__global__ __launch_bounds__(256) void k_gc1(const float* __restrict__ nodes,
                                             const float* __restrict__ W1,
                                             const float* __restrict__ b1,
                                             const float* __restrict__ rs_s,
                                             float* __restrict__ h_pre) {
    __shared__ float Wt[GC_HID][D_FEAT];
    __shared__ float bsh[GC_HID];
    int tid = threadIdx.x;
    for (int idx = tid; idx < D_FEAT * GC_HID; idx += 256) {
        int i = idx / GC_HID, j = idx - i * GC_HID;
        Wt[j][i] = W1[idx];
    }
    if (tid < GC_HID) bsh[tid] = b1[tid];
    __syncthreads();

    int lane = tid & 63;
    int w    = tid >> 6;
    for (int node = blockIdx.x * 4 + w; node < N_NODES; node += gridDim.x * 4) {
        const float4 x = ((const float4*)nodes)[node * (D_FEAT / 4) + lane];
        float p[GC_HID];
#pragma unroll
        for (int j = 0; j < GC_HID; ++j) {
            float4 wv = ((const float4*)&Wt[j][0])[lane];
            p[j] = x.x * wv.x + x.y * wv.y + x.z * wv.z + x.w * wv.w;
        }
#pragma unroll
        for (int m = 32; m >= 1; m >>= 1) {
#pragma unroll
            for (int j = 0; j < GC_HID; ++j) p[j] += __shfl_xor(p[j], m, 64);
        }
        float mx = -1e30f;
#pragma unroll
        for (int j = 0; j < GC_HID; ++j) {
            p[j] = fmaxf(p[j] + bsh[j], 0.0f);
            mx = fmaxf(mx, p[j]);
        }
        float s = 0.0f;
#pragma unroll
        for (int j = 0; j < GC_HID; ++j) {
            p[j] = __expf(p[j] - mx);
            s += p[j];
        }
        float inv = rs_s[node] / s;
#pragma unroll
        for (int j = 0; j < GC_HID; ++j) p[j] *= inv;
        if (lane == 0) {
            float4* o = (float4*)&h_pre[node * GC_HID];
            o[0] = make_float4(p[0],  p[1],  p[2],  p[3]);
            o[1] = make_float4(p[4],  p[5],  p[6],  p[7]);
            o[2] = make_float4(p[8],  p[9],  p[10], p[11]);
            o[3] = make_float4(p[12], p[13], p[14], p[15]);
            o[4] = make_float4(p[16], p[17], p[18], p[19]);
        }
    }
}

// GC layer 2 transform (input pre-scaled by rs_r): h2_pre = softmax(relu(h1@W2+b2))*rs_s
__global__ __launch_bounds__(256) void k_gc2(const float* __restrict__ h1in,
                                             const float* __restrict__ W2,
                                             const float* __restrict__ b2,
                                             const float* __restrict__ rs_s,
                                             float* __restrict__ h2_pre) {
    __shared__ float Wsh[GC_HID * GC_HID];
    __shared__ float bsh[GC_HID];
    int tid = threadIdx.x;
    if (tid < GC_HID * GC_HID) Wsh[tid] = W2[tid];
    if (tid < GC_HID) bsh[tid] = b2[tid];
    __syncthreads();
    int node = blockIdx.x * 256 + tid;
    if (node >= N_NODES) return;
    const float4* ap = (const float4*)&h1in[node * GC_HID];
    float4 a0 = ap[0], a1 = ap[1], a2 = ap[2], a3 = ap[3], a4 = ap[4];
    float h1[GC_HID] = {a0.x,a0.y,a0.z,a0.w, a1.x,a1.y,a1.z,a1.w,
                        a2.x,a2.y,a2.z,a2.w, a3.x,a3.y,a3.z,a3.w,
                        a4.x,a4.y,a4.z,a4.w};
    float t[GC_HID];
#pragma unroll
    for (int j = 0; j < GC_HID; ++j) t[j] = bsh[j];
#pragma unroll
    for (int i = 0; i < GC_HID; ++i) {
        float x = h1[i];
#pragma unroll
        for (int j = 0; j < GC_HID; ++j) t[j] = fmaf(x, Wsh[i * GC_HID + j], t[j]);
    }
    float mx = -1e30f;
#pragma unroll
    for (int j = 0; j < GC_HID; ++j) { t[j] = fmaxf(t[j], 0.0f); mx = fmaxf(mx, t[j]); }
    float s = 0.0f;
#pragma unroll
    for (int j = 0; j < GC_HID; ++j) { t[j] = __expf(t[j] - mx); s += t[j]; }
    float inv = rs_s[node] / s;
#pragma unroll
    for (int j = 0; j < GC_HID; ++j) t[j] *= inv;
    float4* o = (float4*)&h2_pre[node * GC_HID];
    o[0] = make_float4(t[0],  t[1],  t[2],  t[3]);
    o[1] = make_float4(t[4],  t[5],  t[6],  t[7]);
    o[2] = make_float4(t[8],  t[9],  t[10], t[11]);
    o[3] = make_float4(t[12], t[13], t[14], t[15]);
    o[4] = make_float4(t[16], t[17], t[18], t[19]);
}

// encoder head: hcat=[h2, nodes]; mu/logsig2; z
__global__ __launch_bounds__(256) void k_enc(const float* __restrict__ h2in,
                                             const float* __restrict__ nodes,
                                             const float* __restrict__ eps,
                                             const float* __restrict__ Wmu,
                                             const float* __restrict__ bmu,
                                             const float* __restrict__ Wls,
                                             const float* __restrict__ bls,
                                             float* __restrict__ mu_out,
                                             float* __restrict__ ls_out,
                                             float* __restrict__ z) {
    int node = blockIdx.x * 256 + threadIdx.x;
    if (node >= N_NODES) return;
    float accm[Z_DIM], accl[Z_DIM];
#pragma unroll
    for (int j = 0; j < Z_DIM; ++j) { accm[j] = bmu[j]; accl[j] = bls[j]; }

    const float4* ap = (const float4*)&h2in[node * GC_HID];
    float4 a0 = ap[0], a1 = ap[1], a2 = ap[2], a3 = ap[3], a4 = ap[4];
    float h2[GC_HID] = {a0.x,a0.y,a0.z,a0.w, a1.x,a1.y,a1.z,a1.w,
                        a2.x,a2.y,a2.z,a2.w, a3.x,a3.y,a3.z,a3.w,
                        a4.x,a4.y,a4.z,a4.w};
#pragma unroll
    for (int i = 0; i < GC_HID; ++i) {
        float x = h2[i];
#pragma unroll
        for (int j = 0; j < Z_DIM; ++j) {
            accm[j] = fmaf(x, Wmu[i * Z_DIM + j], accm[j]);
            accl[j] = fmaf(x, Wls[i * Z_DIM + j], accl[j]);
        }
    }
    const float4* np = (const float4*)&nodes[node * D_FEAT];
    for (int i4 = 0; i4 < D_FEAT / 4; ++i4) {
        float4 xx = np[i4];
        int row = GC_HID + i4 * 4;
#pragma unroll
        for (int c = 0; c < 4; ++c) {
            float x = (c == 0) ? xx.x : (c == 1) ? xx.y : (c == 2) ? xx.z : xx.w;
#pragma unroll
            for (int j = 0; j < Z_DIM; ++j) {
                accm[j] = fmaf(x, Wmu[(row + c) * Z_DIM + j], accm[j]);
                accl[j] = fmaf(x, Wls[(row + c) * Z_DIM + j], accl[j]);
            }
        }
    }
    const float4* ep = (const float4*)&eps[node * Z_DIM];
    float4* mo = (float4*)&mu_out[node * Z_DIM];
    float4* lo = (float4*)&ls_out[node * Z_DIM];
    float4* zo = (float4*)&z[node * Z_DIM];
#pragma unroll
    for (int q = 0; q < Z_DIM / 4; ++q) {
        float4 ev = ep[q];
        float4 m4 = make_float4(accm[4*q], accm[4*q+1], accm[4*q+2], accm[4*q+3]);
        float4 l4 = make_float4(accl[4*q], accl[4*q+1], accl[4*q+2], accl[4*q+3]);
        mo[q] = m4;
        lo[q] = l4;
        float4 zz;
        zz.x = m4.x + (1e-4f + __expf(0.5f * l4.x)) * ev.x;
        zz.y = m4.y + (1e-4f + __expf(0.5f * l4.y)) * ev.y;
        zz.z = m4.z + (1e-4f + __expf(0.5f * l4.z)) * ev.z;
        zz.w = m4.w + (1e-4f + __expf(0.5f * l4.w)) * ev.w;
        zo[q] = zz;
    }
}

// decoder: d = relu(z@Wd1+bd1); X = d@Wd2+bd2
__global__ __launch_bounds__(256) void k_dec(const float* __restrict__ z,
                                             const float* __restrict__ Wd1,
                                             const float* __restrict__ bd1,
                                             const float* __restrict__ Wd2,
                                             const float* __restrict__ bd2,
                                             float* __restrict__ X) {
    int node = blockIdx.x * 256 + threadIdx.x;
    if (node >= N_NODES) return;
    float zv[Z_DIM];
    const float4* zp = (const float4*)&z[node * Z_DIM];
#pragma unroll
    for (int q = 0; q < Z_DIM / 4; ++q) {
        float4 v = zp[q];
        zv[4*q] = v.x; zv[4*q+1] = v.y; zv[4*q+2] = v.z; zv[4*q+3] = v.w;
    }
    float d[DEC_HID];
#pragma unroll
    for (int j = 0; j < DEC_HID; ++j) d[j] = bd1[j];
#pragma unroll
    for (int i = 0; i < Z_DIM; ++i) {
        float x = zv[i];
#pragma unroll
        for (int j = 0; j < DEC_HID; ++j) d[j] = fmaf(x, Wd1[i * DEC_HID + j], d[j]);
    }
#pragma unroll
    for (int j = 0; j < DEC_HID; ++j) d[j] = fmaxf(d[j], 0.0f);

    float4* xp = (float4*)&X[node * D_FEAT];
    for (int ch = 0; ch < 4; ++ch) {
        float o[64];
#pragma unroll
        for (int j = 0; j < 64; ++j) o[j] = bd2[ch * 64 + j];
#pragma unroll
        for (int i = 0; i < DEC_HID; ++i) {
            float x = d[i];
#pragma unroll
            for (int j = 0; j < 64; ++j)
                o[j] = fmaf(x, Wd2[i * 256 + ch * 64 + j], o[j]);
        }
#pragma unroll
        for (int q = 0; q < 16; ++q)
            xp[ch * 16 + q] = make_float4(o[4*q], o[4*q+1], o[4*q+2], o[4*q+3]);
    }
}

extern "C" void kernel_launch(void* const* d_in, const int* in_sizes, int n_in,
                              void* d_out, int out_size, void* d_ws, size_t ws_size,
                              hipStream_t stream) {
    const float* nodes = (const float*)d_in[0];
    const int*   snd   = (const int*)d_in[1];
    const int*   rcv   = (const int*)d_in[2];
    const float* eps   = (const float*)d_in[3];
    const float* W1    = (const float*)d_in[4];
    const float* b1    = (const float*)d_in[5];
    const float* W2    = (const float*)d_in[6];
    const float* b2    = (const float*)d_in[7];
    const float* Wmu   = (const float*)d_in[8];
    const float* bmu   = (const float*)d_in[9];
    const float* Wls   = (const float*)d_in[10];
    const float* bls   = (const float*)d_in[11];
    const float* Wd1   = (const float*)d_in[12];
    const float* bd1   = (const float*)d_in[13];
    const float* Wd2   = (const float*)d_in[14];
    const float* bd2   = (const float*)d_in[15];

    char* ws = (char*)d_ws;
    float*          h_pre  = (float*)(ws);
    float*          agg    = (float*)(ws + 8000000);
    float*          zbuf   = (float*)(ws + 16000000);
    unsigned*       rec_r  = (unsigned*)(ws + 28800000);
    unsigned short* rec_s  = (unsigned short*)(ws + 41604096);
    unsigned short* srow_r = (unsigned short*)(ws + 48006144);
    unsigned short* srow_s = (unsigned short*)(ws + 48622000);
    float*          rs_s   = (float*)(ws + 49237824);

    float* X      = (float*)d_out;
    float* mu_out = X + (size_t)N_NODES * D_FEAT;
    float* ls_out = mu_out + (size_t)N_NODES * Z_DIM;

    k_sort<<<NBLK, 256, 0, stream>>>(snd, rcv, rec_r, rec_s, srow_r, srow_s);
    k_degs<<<SB, 512, 0, stream>>>(rec_s, srow_s, rs_s);
    k_gc1<<<2048, 256, 0, stream>>>(nodes, W1, b1, rs_s, h_pre);
    k_aggB<<<SB, 512, 0, stream>>>(rec_r, srow_r, h_pre, agg);
    k_gc2<<<391, 256, 0, stream>>>(agg, W2, b2, rs_s, h_pre);
    k_aggB<<<SB, 512, 0, stream>>>(rec_r, srow_r, h_pre, agg);
    k_enc<<<391, 256, 0, stream>>>(agg, nodes, eps, Wmu, bmu, Wls, bls,
                                   mu_out, ls_out, zbuf);
    k_dec<<<391, 256, 0, stream>>>(zbuf, Wd1, bd1, Wd2, bd2, X);
}

// Round 5
// 1454.315 us; speedup vs baseline: 1.1857x; 1.0258x over previous
//
#include <hip/hip_runtime.h>
#include <math.h>

#define N_NODES 100000
#define N_EDGES 3200000
#define D_FEAT 256
#define GC_HID 20
#define DEC_HID 40
#define Z_DIM 32

#define EPB 2048          // edges per sort block
#define NBLK 1563         // ceil(3.2M / 2048)
#define SB 392            // receiver buckets of 256 nodes (392*256 = 100352)
#define SBSH 8
// rec word: (local_r<<17) | sender   (8 + 17 = 25 bits)

// ---------------- ws layout (bytes) ----------------
// h_pre   @ 0           8,000,000
// agg     @ 8,000,000   8,000,000
// grec    @16,000,000  12,804,096  (globally bucket-sorted records)
// zone Z  @28,804,096:
//   rec_r  @28,804,096 12,804,096  (dead after k_gscat)
//   srow_r @41,608,192  1,228,518  (dead after k_gscat)
//   pref_t @42,836,712  2,450,784  (dead after k_gscat)
//   partial@28,804,096 16,056,320  (aggG output; dead after k_mrg)
//   zbuf   @28,804,096 12,800,000  (k_enc output)
// partialc @44,860,416    802,816
// gtot     @45,663,232      1,568
// gbase    @45,664,800      1,572
// deg_s    @45,666,372    400,000   end = 46,066,372

// local counting sort by receiver bucket + deg_s global histogram
__global__ __launch_bounds__(512) void k_sort(const int* __restrict__ snd,
                                              const int* __restrict__ rcv,
                                              unsigned* __restrict__ rec_r,
                                              unsigned short* __restrict__ srow_r,
                                              unsigned* __restrict__ deg_s) {
    __shared__ int es[EPB], er[EPB];
    __shared__ unsigned scan[SB + 1];
    __shared__ unsigned cur[SB];
    __shared__ unsigned sorted[EPB];
    int b = blockIdx.x, t = threadIdx.x;
    int base = b * EPB;
    int cnt = min(EPB, N_EDGES - base);
    for (int i = t; i < cnt; i += 512) { es[i] = snd[base + i]; er[i] = rcv[base + i]; }
    for (int i = t; i < SB + 1; i += 512) scan[i] = 0u;
    __syncthreads();
    for (int i = t; i < cnt; i += 512) {
        atomicAdd(&scan[(er[i] >> SBSH) + 1], 1u);
        atomicAdd(&deg_s[es[i]], 1u);
    }
    __syncthreads();
    for (int off = 1; off < SB + 1; off <<= 1) {
        unsigned v = (t >= off && t < SB + 1) ? scan[t - off] : 0u;
        __syncthreads();
        if (t < SB + 1) scan[t] += v;
        __syncthreads();
    }
    for (int i = t; i < SB + 1; i += 512) srow_r[(size_t)b * (SB + 1) + i] = (unsigned short)scan[i];
    if (t < SB) cur[t] = scan[t];
    __syncthreads();
    for (int i = t; i < cnt; i += 512) {
        int r = er[i];
        unsigned pos = atomicAdd(&cur[r >> SBSH], 1u);
        sorted[pos] = ((unsigned)(r & 255) << 17) | (unsigned)es[i];
    }
    __syncthreads();
    for (int i = t; i < cnt; i += 512) rec_r[(size_t)base + i] = sorted[i];
}

// per-bucket prefix over block segments: pref_t[s][k], totals gtot[s]
__global__ __launch_bounds__(256) void k_scanB(const unsigned short* __restrict__ srow_r,
                                               unsigned* __restrict__ pref_t,
                                               unsigned* __restrict__ gtot) {
    __shared__ unsigned buf[256];
    int s = blockIdx.x, t = threadIdx.x;
    unsigned run = 0;
    for (int k0 = 0; k0 < NBLK; k0 += 256) {
        int k = k0 + t;
        unsigned v = 0;
        if (k < NBLK) {
            const unsigned short* row = srow_r + (size_t)k * (SB + 1);
            v = (unsigned)row[s + 1] - (unsigned)row[s];
        }
        buf[t] = v;
        __syncthreads();
        for (int off = 1; off < 256; off <<= 1) {
            unsigned x = (t >= off) ? buf[t - off] : 0u;
            __syncthreads();
            buf[t] += x;
            __syncthreads();
        }
        if (k < NBLK) pref_t[(size_t)s * NBLK + k] = run + (buf[t] - v);
        unsigned tot = buf[255];
        __syncthreads();
        run += tot;
    }
    if (t == 0) gtot[s] = run;
}

// exclusive scan of bucket totals -> gbase[SB+1]
__global__ __launch_bounds__(512) void k_scanG(const unsigned* __restrict__ gtot,
                                               unsigned* __restrict__ gbase) {
    __shared__ unsigned buf[SB];
    int t = threadIdx.x;
    if (t < SB) buf[t] = gtot[t];
    __syncthreads();
    for (int off = 1; off < SB; off <<= 1) {
        unsigned x = (t >= off && t < SB) ? buf[t - off] : 0u;
        __syncthreads();
        if (t < SB) buf[t] += x;
        __syncthreads();
    }
    if (t < SB) gbase[t + 1] = buf[t];
    if (t == 0) gbase[0] = 0u;
}

// scatter block-sorted records to global bucket-sorted order
__global__ __launch_bounds__(256) void k_gscat(const unsigned* __restrict__ rec_r,
                                               const unsigned short* __restrict__ srow_r,
                                               const unsigned* __restrict__ pref_t,
                                               const unsigned* __restrict__ gbase,
                                               unsigned* __restrict__ grec) {
    __shared__ unsigned recs[EPB];
    __shared__ unsigned short srow[SB + 1];
    int b = blockIdx.x, t = threadIdx.x;
    int base = b * EPB;
    int cnt = min(EPB, N_EDGES - base);
    for (int i = t; i < cnt; i += 256) recs[i] = rec_r[(size_t)base + i];
    for (int i = t; i < SB + 1; i += 256) srow[i] = srow_r[(size_t)b * (SB + 1) + i];
    __syncthreads();
    for (int s = t; s < SB; s += 256) {
        unsigned lo = srow[s], hi = srow[s + 1];
        if (lo == hi) continue;
        unsigned dst = gbase[s] + pref_t[(size_t)s * NBLK + b];
        for (unsigned i = lo; i < hi; ++i) grec[dst + (i - lo)] = recs[i];
    }
}

// aggregation over contiguous bucket range (2 half-blocks per bucket)
__global__ __launch_bounds__(512) void k_aggG(const unsigned* __restrict__ grec,
                                              const unsigned* __restrict__ gbase,
                                              const float* __restrict__ src,
                                              float* __restrict__ partial,
                                              unsigned* __restrict__ partialc) {
    __shared__ float acc[256 * 21];
    __shared__ unsigned cl[256];
    int blk = blockIdx.x;
    int s = blk >> 1, h = blk & 1;
    int t = threadIdx.x;
    for (int i = t; i < 256 * 21; i += 512) acc[i] = 0.0f;
    if (t < 256) cl[t] = 0u;
    __syncthreads();
    unsigned lo = gbase[s], hi = gbase[s + 1];
    unsigned mid = lo + ((hi - lo) >> 1);
    unsigned a = h ? mid : lo;
    unsigned bnd = h ? hi : mid;
    for (unsigned i = a + t; i < bnd; i += 512) {
        unsigned rec = grec[i];
        unsigned sn = rec & 0x1FFFFu;
        unsigned lr = rec >> 17;
        const float4* sp = (const float4*)(src + (size_t)sn * GC_HID);
        float4 A = sp[0], B = sp[1], C = sp[2], D = sp[3], E = sp[4];
        atomicAdd(&cl[lr], 1u);
        float* row = &acc[lr * 21];
        atomicAdd(row + 0,  A.x);  atomicAdd(row + 1,  A.y);
        atomicAdd(row + 2,  A.z);  atomicAdd(row + 3,  A.w);
        atomicAdd(row + 4,  B.x);  atomicAdd(row + 5,  B.y);
        atomicAdd(row + 6,  B.z);  atomicAdd(row + 7,  B.w);
        atomicAdd(row + 8,  C.x);  atomicAdd(row + 9,  C.y);
        atomicAdd(row + 10, C.z);  atomicAdd(row + 11, C.w);
        atomicAdd(row + 12, D.x);  atomicAdd(row + 13, D.y);
        atomicAdd(row + 14, D.z);  atomicAdd(row + 15, D.w);
        atomicAdd(row + 16, E.x);  atomicAdd(row + 17, E.y);
        atomicAdd(row + 18, E.z);  atomicAdd(row + 19, E.w);
    }
    __syncthreads();
    float* pout = partial + (size_t)blk * (256 * GC_HID);
    for (int i = t; i < 256 * GC_HID; i += 512) {
        int r = i / GC_HID, j = i - r * GC_HID;
        pout[i] = acc[r * 21 + j];
    }
    if (t < 256) partialc[blk * 256 + t] = cl[t];
}

// merge halves + receiver normalization
__global__ __launch_bounds__(256) void k_mrg(const float* __restrict__ partial,
                                             const unsigned* __restrict__ partialc,
                                             float* __restrict__ dst) {
    int n = blockIdx.x * 256 + threadIdx.x;
    if (n >= N_NODES) return;
    int s = n >> SBSH, r = n & 255;
    const float4* p0 = (const float4*)(partial + ((size_t)(2 * s) * 256 + r) * GC_HID);
    const float4* p1 = (const float4*)(partial + ((size_t)(2 * s + 1) * 256 + r) * GC_HID);
    unsigned c = partialc[(2 * s) * 256 + r] + partialc[(2 * s + 1) * 256 + r];
    float sc = rsqrtf(fmaxf((float)c, 1.0f));
    float4* o = (float4*)(dst + (size_t)n * GC_HID);
#pragma unroll
    for (int q = 0; q < 5; ++q) {
        float4 x = p0[q], y = p1[q];
        o[q] = make_float4((x.x + y.x) * sc, (x.y + y.y) * sc,
                           (x.z + y.z) * sc, (x.w + y.w) * sc);
    }
}

// GC layer 1 transform: h_pre[n] = softmax(relu(nodes[n] @ W1 + b1)) * rs_s[n]
__global__ __launch_bounds__(256) void k_gc1(const float* __restrict__ nodes,
                                             const float* __restrict__ W1,
                                             const float* __restrict__ b1,
                                             const unsigned* __restrict__ deg_s,
                                             float* __restrict__ h_pre) {
    __shared__ float Wt[GC_HID][D_FEAT];
    __shared__ float bsh[GC_HID];
    int tid = threadIdx.x;
    for (int idx = tid; idx < D_FEAT * GC_HID; idx += 256) {
        int i = idx / GC_HID, j = idx - i * GC_HID;
        Wt[j][i] = W1[idx];
    }
    if (tid < GC_HID) bsh[tid] = b1[tid];
    __syncthreads();

    int lane = tid & 63;
    int w    = tid >> 6;
    for (int node = blockIdx.x * 4 + w; node < N_NODES; node += gridDim.x * 4) {
        const float4 x = ((const float4*)nodes)[node * (D_FEAT / 4) + lane];
        float p[GC_HID];
#pragma unroll
        for (int j = 0; j < GC_HID; ++j) {
            float4 wv = ((const float4*)&Wt[j][0])[lane];
            p[j] = x.x * wv.x + x.y * wv.y + x.z * wv.z + x.w * wv.w;
        }
#pragma unroll
        for (int m = 32; m >= 1; m >>= 1) {
#pragma unroll
            for (int j = 0; j < GC_HID; ++j) p[j] += __shfl_xor(p[j], m, 64);
        }
        float mx = -1e30f;
#pragma unroll
        for (int j = 0; j < GC_HID; ++j) {
            p[j] = fmaxf(p[j] + bsh[j], 0.0f);
            mx = fmaxf(mx, p[j]);
        }
        float s = 0.0f;
#pragma unroll
        for (int j = 0; j < GC_HID; ++j) {
            p[j] = __expf(p[j] - mx);
            s += p[j];
        }
        float inv = rsqrtf(fmaxf((float)deg_s[node], 1.0f)) / s;
#pragma unroll
        for (int j = 0; j < GC_HID; ++j) p[j] *= inv;
        if (lane == 0) {
            float4* o = (float4*)&h_pre[node * GC_HID];
            o[0] = make_float4(p[0],  p[1],  p[2],  p[3]);
            o[1] = make_float4(p[4],  p[5],  p[6],  p[7]);
            o[2] = make_float4(p[8],  p[9],  p[10], p[11]);
            o[3] = make_float4(p[12], p[13], p[14], p[15]);
            o[4] = make_float4(p[16], p[17], p[18], p[19]);
        }
    }
}

// GC layer 2 transform: h2_pre = softmax(relu(h1@W2+b2)) * rs_s
__global__ __launch_bounds__(256) void k_gc2(const float* __restrict__ h1in,
                                             const float* __restrict__ W2,
                                             const float* __restrict__ b2,
                                             const unsigned* __restrict__ deg_s,
                                             float* __restrict__ h2_pre) {
    __shared__ float Wsh[GC_HID * GC_HID];
    __shared__ float bsh[GC_HID];
    int tid = threadIdx.x;
    if (tid < GC_HID * GC_HID) Wsh[tid] = W2[tid];
    if (tid < GC_HID) bsh[tid] = b2[tid];
    __syncthreads();
    int node = blockIdx.x * 256 + tid;
    if (node >= N_NODES) return;
    const float4* ap = (const float4*)&h1in[node * GC_HID];
    float4 a0 = ap[0], a1 = ap[1], a2 = ap[2], a3 = ap[3], a4 = ap[4];
    float h1[GC_HID] = {a0.x,a0.y,a0.z,a0.w, a1.x,a1.y,a1.z,a1.w,
                        a2.x,a2.y,a2.z,a2.w, a3.x,a3.y,a3.z,a3.w,
                        a4.x,a4.y,a4.z,a4.w};
    float t[GC_HID];
#pragma unroll
    for (int j = 0; j < GC_HID; ++j) t[j] = bsh[j];
#pragma unroll
    for (int i = 0; i < GC_HID; ++i) {
        float x = h1[i];
#pragma unroll
        for (int j = 0; j < GC_HID; ++j) t[j] = fmaf(x, Wsh[i * GC_HID + j], t[j]);
    }
    float mx = -1e30f;
#pragma unroll
    for (int j = 0; j < GC_HID; ++j) { t[j] = fmaxf(t[j], 0.0f); mx = fmaxf(mx, t[j]); }
    float s = 0.0f;
#pragma unroll
    for (int j = 0; j < GC_HID; ++j) { t[j] = __expf(t[j] - mx); s += t[j]; }
    float inv = rsqrtf(fmaxf((float)deg_s[node], 1.0f)) / s;
#pragma unroll
    for (int j = 0; j < GC_HID; ++j) t[j] *= inv;
    float4* o = (float4*)&h2_pre[node * GC_HID];
    o[0] = make_float4(t[0],  t[1],  t[2],  t[3]);
    o[1] = make_float4(t[4],  t[5],  t[6],  t[7]);
    o[2] = make_float4(t[8],  t[9],  t[10], t[11]);
    o[3] = make_float4(t[12], t[13], t[14], t[15]);
    o[4] = make_float4(t[16], t[17], t[18], t[19]);
}

// encoder head: hcat=[h2, nodes]; mu/logsig2; z
__global__ __launch_bounds__(256) void k_enc(const float* __restrict__ h2in,
                                             const float* __restrict__ nodes,
                                             const float* __restrict__ eps,
                                             const float* __restrict__ Wmu,
                                             const float* __restrict__ bmu,
                                             const float* __restrict__ Wls,
                                             const float* __restrict__ bls,
                                             float* __restrict__ mu_out,
                                             float* __restrict__ ls_out,
                                             float* __restrict__ z) {
    int node = blockIdx.x * 256 + threadIdx.x;
    if (node >= N_NODES) return;
    float accm[Z_DIM], accl[Z_DIM];
#pragma unroll
    for (int j = 0; j < Z_DIM; ++j) { accm[j] = bmu[j]; accl[j] = bls[j]; }

    const float4* ap = (const float4*)&h2in[node * GC_HID];
    float4 a0 = ap[0], a1 = ap[1], a2 = ap[2], a3 = ap[3], a4 = ap[4];
    float h2[GC_HID] = {a0.x,a0.y,a0.z,a0.w, a1.x,a1.y,a1.z,a1.w,
                        a2.x,a2.y,a2.z,a2.w, a3.x,a3.y,a3.z,a3.w,
                        a4.x,a4.y,a4.z,a4.w};
#pragma unroll
    for (int i = 0; i < GC_HID; ++i) {
        float x = h2[i];
#pragma unroll
        for (int j = 0; j < Z_DIM; ++j) {
            accm[j] = fmaf(x, Wmu[i * Z_DIM + j], accm[j]);
            accl[j] = fmaf(x, Wls[i * Z_DIM + j], accl[j]);
        }
    }
    const float4* np = (const float4*)&nodes[node * D_FEAT];
    for (int i4 = 0; i4 < D_FEAT / 4; ++i4) {
        float4 xx = np[i4];
        int row = GC_HID + i4 * 4;
#pragma unroll
        for (int c = 0; c < 4; ++c) {
            float x = (c == 0) ? xx.x : (c == 1) ? xx.y : (c == 2) ? xx.z : xx.w;
#pragma unroll
            for (int j = 0; j < Z_DIM; ++j) {
                accm[j] = fmaf(x, Wmu[(row + c) * Z_DIM + j], accm[j]);
                accl[j] = fmaf(x, Wls[(row + c) * Z_DIM + j], accl[j]);
            }
        }
    }
    const float4* ep = (const float4*)&eps[node * Z_DIM];
    float4* mo = (float4*)&mu_out[node * Z_DIM];
    float4* lo = (float4*)&ls_out[node * Z_DIM];
    float4* zo = (float4*)&z[node * Z_DIM];
#pragma unroll
    for (int q = 0; q < Z_DIM / 4; ++q) {
        float4 ev = ep[q];
        float4 m4 = make_float4(accm[4*q], accm[4*q+1], accm[4*q+2], accm[4*q+3]);
        float4 l4 = make_float4(accl[4*q], accl[4*q+1], accl[4*q+2], accl[4*q+3]);
        mo[q] = m4;
        lo[q] = l4;
        float4 zz;
        zz.x = m4.x + (1e-4f + __expf(0.5f * l4.x)) * ev.x;
        zz.y = m4.y + (1e-4f + __expf(0.5f * l4.y)) * ev.y;
        zz.z = m4.z + (1e-4f + __expf(0.5f * l4.z)) * ev.z;
        zz.w = m4.w + (1e-4f + __expf(0.5f * l4.w)) * ev.w;
        zo[q] = zz;
    }
}

// decoder: d = relu(z@Wd1+bd1); X = d@Wd2+bd2
__global__ __launch_bounds__(256) void k_dec(const float* __restrict__ z,
                                             const float* __restrict__ Wd1,
                                             const float* __restrict__ bd1,
                                             const float* __restrict__ Wd2,
                                             const float* __restrict__ bd2,
                                             float* __restrict__ X) {
    int node = blockIdx.x * 256 + threadIdx.x;
    if (node >= N_NODES) return;
    float zv[Z_DIM];
    const float4* zp = (const float4*)&z[node * Z_DIM];
#pragma unroll
    for (int q = 0; q < Z_DIM / 4; ++q) {
        float4 v = zp[q];
        zv[4*q] = v.x; zv[4*q+1] = v.y; zv[4*q+2] = v.z; zv[4*q+3] = v.w;
    }
    float d[DEC_HID];
#pragma unroll
    for (int j = 0; j < DEC_HID; ++j) d[j] = bd1[j];
#pragma unroll
    for (int i = 0; i < Z_DIM; ++i) {
        float x = zv[i];
#pragma unroll
        for (int j = 0; j < DEC_HID; ++j) d[j] = fmaf(x, Wd1[i * DEC_HID + j], d[j]);
    }
#pragma unroll
    for (int j = 0; j < DEC_HID; ++j) d[j] = fmaxf(d[j], 0.0f);

    float4* xp = (float4*)&X[node * D_FEAT];
    for (int ch = 0; ch < 4; ++ch) {
        float o[64];
#pragma unroll
        for (int j = 0; j < 64; ++j) o[j] = bd2[ch * 64 + j];
#pragma unroll
        for (int i = 0; i < DEC_HID; ++i) {
            float x = d[i];
#pragma unroll
            for (int j = 0; j < 64; ++j)
                o[j] = fmaf(x, Wd2[i * 256 + ch * 64 + j], o[j]);
        }
#pragma unroll
        for (int q = 0; q < 16; ++q)
            xp[ch * 16 + q] = make_float4(o[4*q], o[4*q+1], o[4*q+2], o[4*q+3]);
    }
}

extern "C" void kernel_launch(void* const* d_in, const int* in_sizes, int n_in,
                              void* d_out, int out_size, void* d_ws, size_t ws_size,
                              hipStream_t stream) {
    const float* nodes = (const float*)d_in[0];
    const int*   snd   = (const int*)d_in[1];
    const int*   rcv   = (const int*)d_in[2];
    const float* eps   = (const float*)d_in[3];
    const float* W1    = (const float*)d_in[4];
    const float* b1    = (const float*)d_in[5];
    const float* W2    = (const float*)d_in[6];
    const float* b2    = (const float*)d_in[7];
    const float* Wmu   = (const float*)d_in[8];
    const float* bmu   = (const float*)d_in[9];
    const float* Wls   = (const float*)d_in[10];
    const float* bls   = (const float*)d_in[11];
    const float* Wd1   = (const float*)d_in[12];
    const float* bd1   = (const float*)d_in[13];
    const float* Wd2   = (const float*)d_in[14];
    const float* bd2   = (const float*)d_in[15];

    char* ws = (char*)d_ws;
    float*          h_pre    = (float*)(ws);
    float*          agg      = (float*)(ws + 8000000);
    unsigned*       grec     = (unsigned*)(ws + 16000000);
    unsigned*       rec_r    = (unsigned*)(ws + 28804096);
    unsigned short* srow_r   = (unsigned short*)(ws + 41608192);
    unsigned*       pref_t   = (unsigned*)(ws + 42836712);
    float*          partial  = (float*)(ws + 28804096);   // reuses rec_r zone after gscat
    float*          zbuf     = (float*)(ws + 28804096);   // reuses zone after last mrg
    unsigned*       partialc = (unsigned*)(ws + 44860416);
    unsigned*       gtot     = (unsigned*)(ws + 45663232);
    unsigned*       gbase    = (unsigned*)(ws + 45664800);
    unsigned*       deg_s    = (unsigned*)(ws + 45666372);

    float* X      = (float*)d_out;
    float* mu_out = X + (size_t)N_NODES * D_FEAT;
    float* ls_out = mu_out + (size_t)N_NODES * Z_DIM;

    hipMemsetAsync(deg_s, 0, 400000, stream);

    k_sort<<<NBLK, 512, 0, stream>>>(snd, rcv, rec_r, srow_r, deg_s);
    k_scanB<<<SB, 256, 0, stream>>>(srow_r, pref_t, gtot);
    k_scanG<<<1, 512, 0, stream>>>(gtot, gbase);
    k_gscat<<<NBLK, 256, 0, stream>>>(rec_r, srow_r, pref_t, gbase, grec);

    k_gc1<<<2048, 256, 0, stream>>>(nodes, W1, b1, deg_s, h_pre);
    k_aggG<<<2 * SB, 512, 0, stream>>>(grec, gbase, h_pre, partial, partialc);
    k_mrg<<<391, 256, 0, stream>>>(partial, partialc, agg);
    k_gc2<<<391, 256, 0, stream>>>(agg, W2, b2, deg_s, h_pre);
    k_aggG<<<2 * SB, 512, 0, stream>>>(grec, gbase, h_pre, partial, partialc);
    k_mrg<<<391, 256, 0, stream>>>(partial, partialc, agg);
    k_enc<<<391, 256, 0, stream>>>(agg, nodes, eps, Wmu, bmu, Wls, bls,
                                   mu_out, ls_out, zbuf);
    k_dec<<<391, 256, 0, stream>>>(zbuf, Wd1, bd1, Wd2, bd2, X);
}

// Round 6
// 801.497 us; speedup vs baseline: 2.1515x; 1.8145x over previous
//
#include <hip/hip_runtime.h>
#include <math.h>

#define N_NODES 100000
#define N_EDGES 3200000
#define D_FEAT 256
#define GC_HID 20
#define DEC_HID 40
#define Z_DIM 32

#define EPB 2048          // edges per sort block
#define NBLK 1563         // ceil(3.2M / 2048)
#define SB 392            // receiver buckets of 256 nodes (392*256 = 100352)
#define SBSH 8
#define S2CAP 12288       // per-bucket record cap (mean 8192, sigma~90 -> +45 sigma)
// rec word (stage 1): (local_r<<17) | sender ; after k_sort2: sender only

// ---------------- ws layout (bytes) ----------------
// h_pre  @ 0           8,000,000
// agg    @ 8,000,000   8,000,000
// grec   @16,000,000  12,804,096  (bucket-sorted, then fully sorted in-place)
// zone Z @28,804,096:
//   rec_r  @28,804,096 12,804,096  (dead after k_gscat)
//   srow_r @41,608,192  1,228,518  (dead after k_gscat)
//   pref_t @42,836,720  2,450,784  (dead after k_gscat)
//   zbuf   @28,804,096 12,800,000  (k_enc output, after gscat)
// row_ptr @45,287,504    400,004
// gtot    @45,687,508      1,568
// gbase   @45,689,076      1,572
// deg_s   @45,690,648    400,000   end = 46,090,648

// local counting sort by receiver bucket + deg_s global histogram
__global__ __launch_bounds__(512) void k_sort(const int* __restrict__ snd,
                                              const int* __restrict__ rcv,
                                              unsigned* __restrict__ rec_r,
                                              unsigned short* __restrict__ srow_r,
                                              unsigned* __restrict__ deg_s) {
    __shared__ int es[EPB], er[EPB];
    __shared__ unsigned scan[SB + 1];
    __shared__ unsigned cur[SB];
    __shared__ unsigned sorted[EPB];
    int b = blockIdx.x, t = threadIdx.x;
    int base = b * EPB;
    int cnt = min(EPB, N_EDGES - base);
    for (int i = t; i < cnt; i += 512) { es[i] = snd[base + i]; er[i] = rcv[base + i]; }
    for (int i = t; i < SB + 1; i += 512) scan[i] = 0u;
    __syncthreads();
    for (int i = t; i < cnt; i += 512) {
        atomicAdd(&scan[(er[i] >> SBSH) + 1], 1u);
        atomicAdd(&deg_s[es[i]], 1u);
    }
    __syncthreads();
    for (int off = 1; off < SB + 1; off <<= 1) {
        unsigned v = (t >= off && t < SB + 1) ? scan[t - off] : 0u;
        __syncthreads();
        if (t < SB + 1) scan[t] += v;
        __syncthreads();
    }
    for (int i = t; i < SB + 1; i += 512) srow_r[(size_t)b * (SB + 1) + i] = (unsigned short)scan[i];
    if (t < SB) cur[t] = scan[t];
    __syncthreads();
    for (int i = t; i < cnt; i += 512) {
        int r = er[i];
        unsigned pos = atomicAdd(&cur[r >> SBSH], 1u);
        sorted[pos] = ((unsigned)(r & 255) << 17) | (unsigned)es[i];
    }
    __syncthreads();
    for (int i = t; i < cnt; i += 512) rec_r[(size_t)base + i] = sorted[i];
}

// per-bucket prefix over block segments: pref_t[s][k], totals gtot[s]
__global__ __launch_bounds__(256) void k_scanB(const unsigned short* __restrict__ srow_r,
                                               unsigned* __restrict__ pref_t,
                                               unsigned* __restrict__ gtot) {
    __shared__ unsigned buf[256];
    int s = blockIdx.x, t = threadIdx.x;
    unsigned run = 0;
    for (int k0 = 0; k0 < NBLK; k0 += 256) {
        int k = k0 + t;
        unsigned v = 0;
        if (k < NBLK) {
            const unsigned short* row = srow_r + (size_t)k * (SB + 1);
            v = (unsigned)row[s + 1] - (unsigned)row[s];
        }
        buf[t] = v;
        __syncthreads();
        for (int off = 1; off < 256; off <<= 1) {
            unsigned x = (t >= off) ? buf[t - off] : 0u;
            __syncthreads();
            buf[t] += x;
            __syncthreads();
        }
        if (k < NBLK) pref_t[(size_t)s * NBLK + k] = run + (buf[t] - v);
        unsigned tot = buf[255];
        __syncthreads();
        run += tot;
    }
    if (t == 0) gtot[s] = run;
}

// exclusive scan of bucket totals -> gbase[SB+1]
__global__ __launch_bounds__(512) void k_scanG(const unsigned* __restrict__ gtot,
                                               unsigned* __restrict__ gbase) {
    __shared__ unsigned buf[SB];
    int t = threadIdx.x;
    if (t < SB) buf[t] = gtot[t];
    __syncthreads();
    for (int off = 1; off < SB; off <<= 1) {
        unsigned x = (t >= off && t < SB) ? buf[t - off] : 0u;
        __syncthreads();
        if (t < SB) buf[t] += x;
        __syncthreads();
    }
    if (t < SB) gbase[t + 1] = buf[t];
    if (t == 0) gbase[0] = 0u;
}

// scatter block-sorted records to global bucket-sorted order
__global__ __launch_bounds__(256) void k_gscat(const unsigned* __restrict__ rec_r,
                                               const unsigned short* __restrict__ srow_r,
                                               const unsigned* __restrict__ pref_t,
                                               const unsigned* __restrict__ gbase,
                                               unsigned* __restrict__ grec) {
    __shared__ unsigned recs[EPB];
    __shared__ unsigned short srow[SB + 1];
    int b = blockIdx.x, t = threadIdx.x;
    int base = b * EPB;
    int cnt = min(EPB, N_EDGES - base);
    for (int i = t; i < cnt; i += 256) recs[i] = rec_r[(size_t)base + i];
    for (int i = t; i < SB + 1; i += 256) srow[i] = srow_r[(size_t)b * (SB + 1) + i];
    __syncthreads();
    for (int s = t; s < SB; s += 256) {
        unsigned lo = srow[s], hi = srow[s + 1];
        if (lo == hi) continue;
        unsigned dst = gbase[s] + pref_t[(size_t)s * NBLK + b];
        for (unsigned i = lo; i < hi; ++i) grec[dst + (i - lo)] = recs[i];
    }
}

// within-bucket counting sort by local receiver (in-place) + CSR row_ptr
__global__ __launch_bounds__(256) void k_sort2(unsigned* __restrict__ grec,
                                               const unsigned* __restrict__ gbase,
                                               unsigned* __restrict__ row_ptr) {
    __shared__ unsigned recs[S2CAP];     // 48 KB
    __shared__ unsigned hist[256];
    __shared__ unsigned scan[256];
    __shared__ unsigned cur[256];
    int s = blockIdx.x, t = threadIdx.x;
    unsigned lo = gbase[s], hi = gbase[s + 1];
    unsigned cnt = min(hi - lo, (unsigned)S2CAP);
    for (unsigned i = t; i < cnt; i += 256) recs[i] = grec[lo + i];
    hist[t] = 0u;
    __syncthreads();
    for (unsigned i = t; i < cnt; i += 256) atomicAdd(&hist[recs[i] >> 17], 1u);
    __syncthreads();
    unsigned v = hist[t];
    scan[t] = v;
    __syncthreads();
    for (int off = 1; off < 256; off <<= 1) {
        unsigned x = (t >= off) ? scan[t - off] : 0u;
        __syncthreads();
        scan[t] += x;
        __syncthreads();
    }
    unsigned excl = scan[t] - v;   // exclusive prefix of bin t
    {
        int n = (s << SBSH) + t;
        if (n <= N_NODES) row_ptr[n] = lo + excl;
    }
    cur[t] = excl;
    __syncthreads();
    for (unsigned i = t; i < cnt; i += 256) {
        unsigned rec = recs[i];
        unsigned pos = atomicAdd(&cur[rec >> 17], 1u);
        grec[lo + pos] = rec & 0x1FFFFu;   // sender only
    }
}

// pure CSR gather: 5 lanes per node, one float4 each; zero atomics
__global__ __launch_bounds__(320) void k_gather(const unsigned* __restrict__ row_ptr,
                                                const unsigned* __restrict__ grec,
                                                const float* __restrict__ src,
                                                float* __restrict__ dst) {
    int gid = blockIdx.x * 320 + threadIdx.x;
    int node = gid / 5, q = gid % 5;
    if (node >= N_NODES) return;
    unsigned lo = row_ptr[node], hi = row_ptr[node + 1];
    float4 acc = make_float4(0.f, 0.f, 0.f, 0.f);
    for (unsigned e = lo; e < hi; ++e) {
        unsigned sn = grec[e];
        float4 v = ((const float4*)src)[sn * 5 + q];
        acc.x += v.x; acc.y += v.y; acc.z += v.z; acc.w += v.w;
    }
    float sc = rsqrtf(fmaxf((float)(hi - lo), 1.0f));
    acc.x *= sc; acc.y *= sc; acc.z *= sc; acc.w *= sc;
    ((float4*)dst)[node * 5 + q] = acc;
}

// GC layer 1 transform: h_pre[n] = softmax(relu(nodes[n] @ W1 + b1)) * rs_s[n]
__global__ __launch_bounds__(256) void k_gc1(const float* __restrict__ nodes,
                                             const float* __restrict__ W1,
                                             const float* __restrict__ b1,
                                             const unsigned* __restrict__ deg_s,
                                             float* __restrict__ h_pre) {
    __shared__ float Wt[GC_HID][D_FEAT];
    __shared__ float bsh[GC_HID];
    int tid = threadIdx.x;
    for (int idx = tid; idx < D_FEAT * GC_HID; idx += 256) {
        int i = idx / GC_HID, j = idx - i * GC_HID;
        Wt[j][i] = W1[idx];
    }
    if (tid < GC_HID) bsh[tid] = b1[tid];
    __syncthreads();

    int lane = tid & 63;
    int w    = tid >> 6;
    for (int node = blockIdx.x * 4 + w; node < N_NODES; node += gridDim.x * 4) {
        const float4 x = ((const float4*)nodes)[node * (D_FEAT / 4) + lane];
        float p[GC_HID];
#pragma unroll
        for (int j = 0; j < GC_HID; ++j) {
            float4 wv = ((const float4*)&Wt[j][0])[lane];
            p[j] = x.x * wv.x + x.y * wv.y + x.z * wv.z + x.w * wv.w;
        }
#pragma unroll
        for (int m = 32; m >= 1; m >>= 1) {
#pragma unroll
            for (int j = 0; j < GC_HID; ++j) p[j] += __shfl_xor(p[j], m, 64);
        }
        float mx = -1e30f;
#pragma unroll
        for (int j = 0; j < GC_HID; ++j) {
            p[j] = fmaxf(p[j] + bsh[j], 0.0f);
            mx = fmaxf(mx, p[j]);
        }
        float s = 0.0f;
#pragma unroll
        for (int j = 0; j < GC_HID; ++j) {
            p[j] = __expf(p[j] - mx);
            s += p[j];
        }
        float inv = rsqrtf(fmaxf((float)deg_s[node], 1.0f)) / s;
#pragma unroll
        for (int j = 0; j < GC_HID; ++j) p[j] *= inv;
        if (lane == 0) {
            float4* o = (float4*)&h_pre[node * GC_HID];
            o[0] = make_float4(p[0],  p[1],  p[2],  p[3]);
            o[1] = make_float4(p[4],  p[5],  p[6],  p[7]);
            o[2] = make_float4(p[8],  p[9],  p[10], p[11]);
            o[3] = make_float4(p[12], p[13], p[14], p[15]);
            o[4] = make_float4(p[16], p[17], p[18], p[19]);
        }
    }
}

// GC layer 2 transform: h2_pre = softmax(relu(h1@W2+b2)) * rs_s
__global__ __launch_bounds__(256) void k_gc2(const float* __restrict__ h1in,
                                             const float* __restrict__ W2,
                                             const float* __restrict__ b2,
                                             const unsigned* __restrict__ deg_s,
                                             float* __restrict__ h2_pre) {
    __shared__ float Wsh[GC_HID * GC_HID];
    __shared__ float bsh[GC_HID];
    int tid = threadIdx.x;
    if (tid < GC_HID * GC_HID) Wsh[tid] = W2[tid];
    if (tid < GC_HID) bsh[tid] = b2[tid];
    __syncthreads();
    int node = blockIdx.x * 256 + tid;
    if (node >= N_NODES) return;
    const float4* ap = (const float4*)&h1in[node * GC_HID];
    float4 a0 = ap[0], a1 = ap[1], a2 = ap[2], a3 = ap[3], a4 = ap[4];
    float h1[GC_HID] = {a0.x,a0.y,a0.z,a0.w, a1.x,a1.y,a1.z,a1.w,
                        a2.x,a2.y,a2.z,a2.w, a3.x,a3.y,a3.z,a3.w,
                        a4.x,a4.y,a4.z,a4.w};
    float t[GC_HID];
#pragma unroll
    for (int j = 0; j < GC_HID; ++j) t[j] = bsh[j];
#pragma unroll
    for (int i = 0; i < GC_HID; ++i) {
        float x = h1[i];
#pragma unroll
        for (int j = 0; j < GC_HID; ++j) t[j] = fmaf(x, Wsh[i * GC_HID + j], t[j]);
    }
    float mx = -1e30f;
#pragma unroll
    for (int j = 0; j < GC_HID; ++j) { t[j] = fmaxf(t[j], 0.0f); mx = fmaxf(mx, t[j]); }
    float s = 0.0f;
#pragma unroll
    for (int j = 0; j < GC_HID; ++j) { t[j] = __expf(t[j] - mx); s += t[j]; }
    float inv = rsqrtf(fmaxf((float)deg_s[node], 1.0f)) / s;
#pragma unroll
    for (int j = 0; j < GC_HID; ++j) t[j] *= inv;
    float4* o = (float4*)&h2_pre[node * GC_HID];
    o[0] = make_float4(t[0],  t[1],  t[2],  t[3]);
    o[1] = make_float4(t[4],  t[5],  t[6],  t[7]);
    o[2] = make_float4(t[8],  t[9],  t[10], t[11]);
    o[3] = make_float4(t[12], t[13], t[14], t[15]);
    o[4] = make_float4(t[16], t[17], t[18], t[19]);
}

// encoder head: hcat=[h2, nodes]; mu/logsig2; z
__global__ __launch_bounds__(256) void k_enc(const float* __restrict__ h2in,
                                             const float* __restrict__ nodes,
                                             const float* __restrict__ eps,
                                             const float* __restrict__ Wmu,
                                             const float* __restrict__ bmu,
                                             const float* __restrict__ Wls,
                                             const float* __restrict__ bls,
                                             float* __restrict__ mu_out,
                                             float* __restrict__ ls_out,
                                             float* __restrict__ z) {
    int node = blockIdx.x * 256 + threadIdx.x;
    if (node >= N_NODES) return;
    float accm[Z_DIM], accl[Z_DIM];
#pragma unroll
    for (int j = 0; j < Z_DIM; ++j) { accm[j] = bmu[j]; accl[j] = bls[j]; }

    const float4* ap = (const float4*)&h2in[node * GC_HID];
    float4 a0 = ap[0], a1 = ap[1], a2 = ap[2], a3 = ap[3], a4 = ap[4];
    float h2[GC_HID] = {a0.x,a0.y,a0.z,a0.w, a1.x,a1.y,a1.z,a1.w,
                        a2.x,a2.y,a2.z,a2.w, a3.x,a3.y,a3.z,a3.w,
                        a4.x,a4.y,a4.z,a4.w};
#pragma unroll
    for (int i = 0; i < GC_HID; ++i) {
        float x = h2[i];
#pragma unroll
        for (int j = 0; j < Z_DIM; ++j) {
            accm[j] = fmaf(x, Wmu[i * Z_DIM + j], accm[j]);
            accl[j] = fmaf(x, Wls[i * Z_DIM + j], accl[j]);
        }
    }
    const float4* np = (const float4*)&nodes[node * D_FEAT];
    for (int i4 = 0; i4 < D_FEAT / 4; ++i4) {
        float4 xx = np[i4];
        int row = GC_HID + i4 * 4;
#pragma unroll
        for (int c = 0; c < 4; ++c) {
            float x = (c == 0) ? xx.x : (c == 1) ? xx.y : (c == 2) ? xx.z : xx.w;
#pragma unroll
            for (int j = 0; j < Z_DIM; ++j) {
                accm[j] = fmaf(x, Wmu[(row + c) * Z_DIM + j], accm[j]);
                accl[j] = fmaf(x, Wls[(row + c) * Z_DIM + j], accl[j]);
            }
        }
    }
    const float4* ep = (const float4*)&eps[node * Z_DIM];
    float4* mo = (float4*)&mu_out[node * Z_DIM];
    float4* lo = (float4*)&ls_out[node * Z_DIM];
    float4* zo = (float4*)&z[node * Z_DIM];
#pragma unroll
    for (int q = 0; q < Z_DIM / 4; ++q) {
        float4 ev = ep[q];
        float4 m4 = make_float4(accm[4*q], accm[4*q+1], accm[4*q+2], accm[4*q+3]);
        float4 l4 = make_float4(accl[4*q], accl[4*q+1], accl[4*q+2], accl[4*q+3]);
        mo[q] = m4;
        lo[q] = l4;
        float4 zz;
        zz.x = m4.x + (1e-4f + __expf(0.5f * l4.x)) * ev.x;
        zz.y = m4.y + (1e-4f + __expf(0.5f * l4.y)) * ev.y;
        zz.z = m4.z + (1e-4f + __expf(0.5f * l4.z)) * ev.z;
        zz.w = m4.w + (1e-4f + __expf(0.5f * l4.w)) * ev.w;
        zo[q] = zz;
    }
}

// decoder: d = relu(z@Wd1+bd1); X = d@Wd2+bd2
__global__ __launch_bounds__(256) void k_dec(const float* __restrict__ z,
                                             const float* __restrict__ Wd1,
                                             const float* __restrict__ bd1,
                                             const float* __restrict__ Wd2,
                                             const float* __restrict__ bd2,
                                             float* __restrict__ X) {
    int node = blockIdx.x * 256 + threadIdx.x;
    if (node >= N_NODES) return;
    float zv[Z_DIM];
    const float4* zp = (const float4*)&z[node * Z_DIM];
#pragma unroll
    for (int q = 0; q < Z_DIM / 4; ++q) {
        float4 v = zp[q];
        zv[4*q] = v.x; zv[4*q+1] = v.y; zv[4*q+2] = v.z; zv[4*q+3] = v.w;
    }
    float d[DEC_HID];
#pragma unroll
    for (int j = 0; j < DEC_HID; ++j) d[j] = bd1[j];
#pragma unroll
    for (int i = 0; i < Z_DIM; ++i) {
        float x = zv[i];
#pragma unroll
        for (int j = 0; j < DEC_HID; ++j) d[j] = fmaf(x, Wd1[i * DEC_HID + j], d[j]);
    }
#pragma unroll
    for (int j = 0; j < DEC_HID; ++j) d[j] = fmaxf(d[j], 0.0f);

    float4* xp = (float4*)&X[node * D_FEAT];
    for (int ch = 0; ch < 4; ++ch) {
        float o[64];
#pragma unroll
        for (int j = 0; j < 64; ++j) o[j] = bd2[ch * 64 + j];
#pragma unroll
        for (int i = 0; i < DEC_HID; ++i) {
            float x = d[i];
#pragma unroll
            for (int j = 0; j < 64; ++j)
                o[j] = fmaf(x, Wd2[i * 256 + ch * 64 + j], o[j]);
        }
#pragma unroll
        for (int q = 0; q < 16; ++q)
            xp[ch * 16 + q] = make_float4(o[4*q], o[4*q+1], o[4*q+2], o[4*q+3]);
    }
}

extern "C" void kernel_launch(void* const* d_in, const int* in_sizes, int n_in,
                              void* d_out, int out_size, void* d_ws, size_t ws_size,
                              hipStream_t stream) {
    const float* nodes = (const float*)d_in[0];
    const int*   snd   = (const int*)d_in[1];
    const int*   rcv   = (const int*)d_in[2];
    const float* eps   = (const float*)d_in[3];
    const float* W1    = (const float*)d_in[4];
    const float* b1    = (const float*)d_in[5];
    const float* W2    = (const float*)d_in[6];
    const float* b2    = (const float*)d_in[7];
    const float* Wmu   = (const float*)d_in[8];
    const float* bmu   = (const float*)d_in[9];
    const float* Wls   = (const float*)d_in[10];
    const float* bls   = (const float*)d_in[11];
    const float* Wd1   = (const float*)d_in[12];
    const float* bd1   = (const float*)d_in[13];
    const float* Wd2   = (const float*)d_in[14];
    const float* bd2   = (const float*)d_in[15];

    char* ws = (char*)d_ws;
    float*          h_pre    = (float*)(ws);
    float*          agg      = (float*)(ws + 8000000);
    unsigned*       grec     = (unsigned*)(ws + 16000000);
    unsigned*       rec_r    = (unsigned*)(ws + 28804096);
    unsigned short* srow_r   = (unsigned short*)(ws + 41608192);
    unsigned*       pref_t   = (unsigned*)(ws + 42836720);
    float*          zbuf     = (float*)(ws + 28804096);   // reuses rec_r zone after gscat
    unsigned*       row_ptr  = (unsigned*)(ws + 45287504);
    unsigned*       gtot     = (unsigned*)(ws + 45687508);
    unsigned*       gbase    = (unsigned*)(ws + 45689076);
    unsigned*       deg_s    = (unsigned*)(ws + 45690648);

    float* X      = (float*)d_out;
    float* mu_out = X + (size_t)N_NODES * D_FEAT;
    float* ls_out = mu_out + (size_t)N_NODES * Z_DIM;

    hipMemsetAsync(deg_s, 0, 400000, stream);

    k_sort<<<NBLK, 512, 0, stream>>>(snd, rcv, rec_r, srow_r, deg_s);
    k_scanB<<<SB, 256, 0, stream>>>(srow_r, pref_t, gtot);
    k_scanG<<<1, 512, 0, stream>>>(gtot, gbase);
    k_gscat<<<NBLK, 256, 0, stream>>>(rec_r, srow_r, pref_t, gbase, grec);
    k_sort2<<<SB, 256, 0, stream>>>(grec, gbase, row_ptr);

    k_gc1<<<2048, 256, 0, stream>>>(nodes, W1, b1, deg_s, h_pre);
    k_gather<<<1563, 320, 0, stream>>>(row_ptr, grec, h_pre, agg);
    k_gc2<<<391, 256, 0, stream>>>(agg, W2, b2, deg_s, h_pre);
    k_gather<<<1563, 320, 0, stream>>>(row_ptr, grec, h_pre, agg);
    k_enc<<<391, 256, 0, stream>>>(agg, nodes, eps, Wmu, bmu, Wls, bls,
                                   mu_out, ls_out, zbuf);
    k_dec<<<391, 256, 0, stream>>>(zbuf, Wd1, bd1, Wd2, bd2, X);
}